// Round 7
// baseline (382.744 us; speedup 1.0000x reference)
//
#include <hip/hip_runtime.h>

// GCN: 2x GCNConv(128->128, relu) + linear(128->40).
// R16: k_count was the top dispatch (67us, VALU 0.5%, HBM 11%, occ 68% ->
// pure atomic round-trip latency, 1 atomic in flight per wave). Fixes:
//   (1) k_count: 4 edges/thread -> 4 independent atomicAdds in flight per
//       lane (int4 dst read, branchless junk-counter redirect for poison,
//       int4 rank write). Same MLP cure as R11's agg.
//   (2) k_fill: same 4-edge MLP batching (4 independent row_start loads +
//       4 scattered stores in flight), AND fused with layer-1 MFMA GEMM
//       into one dispatch (independent work: fill writes col_idx in d_out,
//       gemm reads X/W1/dis writes y-table in X). Interleaved block roles
//       so latency-bound fill waves and MFMA waves co-reside.
// CSR/agg/gemm2/head otherwise unchanged from R15 (374us, absmax 1.95e-3).

typedef unsigned int uint32;
typedef unsigned short u16;

#define FD 128  // F_IN = H1 = H2 = 128 (structural)

using short8 = __attribute__((ext_vector_type(8))) short;
using f32x4  = __attribute__((ext_vector_type(4))) float;

union U4S8 { uint4 u; short8 s; };

__device__ __forceinline__ u16 f2bf(float f) {  // fp32 -> bf16 bits, RNE
    uint32 u = __float_as_uint(f);
    uint32 r = ((u >> 16) & 1u) + 0x7FFFu;
    return (u16)((u + r) >> 16);
}
__device__ __forceinline__ float bf2f(u16 s) { return __uint_as_float((uint32)s << 16); }
__device__ __forceinline__ float bfLo(uint32 w) { return __uint_as_float(w << 16); }
__device__ __forceinline__ float bfHi(uint32 w) { return __uint_as_float(w & 0xFFFF0000u); }

__global__ void k_beacon(float* __restrict__ out, long long n, float val) {
    long long i = (long long)blockIdx.x * 256 + threadIdx.x;
    if (i < n) out[i] = val;
}

// ---------- CSR build ----------
// R16: 4 edges/thread, 4 independent atomics in flight. cnt has nn+1 slots;
// slot nn is the junk counter for poisoned dst (branchless).
__global__ __launch_bounds__(256) void k_count(const int* __restrict__ dst,
                                               int* __restrict__ cnt,
                                               int* __restrict__ rank,
                                               int ne, int nn) {
    long long base = ((long long)blockIdx.x * 256 + threadIdx.x) * 4;
    if (base + 4 <= (long long)ne) {
        int4 d4 = *(const int4*)(dst + base);
        int a0 = ((unsigned)d4.x < (unsigned)nn) ? d4.x : nn;
        int a1 = ((unsigned)d4.y < (unsigned)nn) ? d4.y : nn;
        int a2 = ((unsigned)d4.z < (unsigned)nn) ? d4.z : nn;
        int a3 = ((unsigned)d4.w < (unsigned)nn) ? d4.w : nn;
        int4 r4;
        r4.x = atomicAdd(&cnt[a0], 1);
        r4.y = atomicAdd(&cnt[a1], 1);
        r4.z = atomicAdd(&cnt[a2], 1);
        r4.w = atomicAdd(&cnt[a3], 1);
        *(int4*)(rank + base) = r4;
    } else {
        for (long long e = base; e < (long long)ne; e++) {
            int d = dst[e];
            int a = ((unsigned)d < (unsigned)nn) ? d : nn;
            rank[e] = atomicAdd(&cnt[a], 1);
        }
    }
}

// scan_a + dis fused: block-local exclusive scan of cnt, plus dis=rsqrt(cnt+1).
__global__ void k_scan_a(const int* __restrict__ cnt, int* __restrict__ row_start,
                         int* __restrict__ bsum, float* __restrict__ dis, int nn) {
    __shared__ int tmp[256];
    int t = threadIdx.x;
    int i = blockIdx.x * 256 + t;
    int v = (i < nn) ? cnt[i] : 0;
    if (i < nn) dis[i] = rsqrtf((float)(v + 1));  // +1 self-loop
    tmp[t] = v;
    __syncthreads();
    for (int off = 1; off < 256; off <<= 1) {
        int x = (t >= off) ? tmp[t - off] : 0;
        __syncthreads();
        tmp[t] += x;
        __syncthreads();
    }
    if (i < nn) row_start[i] = tmp[t] - v;
    if (t == 255) bsum[blockIdx.x] = tmp[255];
}

__global__ void k_scan_b(int* bsum, int nb) {  // chunked exclusive scan, any nb
    __shared__ int tmp[512];
    __shared__ int carry;
    int t = threadIdx.x;
    if (t == 0) carry = 0;
    __syncthreads();
    for (int base = 0; base < nb; base += 512) {
        int i = base + t;
        int v = (i < nb) ? bsum[i] : 0;
        tmp[t] = v;
        __syncthreads();
        for (int off = 1; off < 512; off <<= 1) {
            int x = (t >= off) ? tmp[t - off] : 0;
            __syncthreads();
            tmp[t] += x;
            __syncthreads();
        }
        if (i < nb) bsum[i] = tmp[t] - v + carry;
        __syncthreads();
        if (t == 0) carry += tmp[511];
        __syncthreads();
    }
}

__global__ void k_scan_c(int* __restrict__ row_start, const int* __restrict__ bsum,
                         int nn, int ne) {
    int i = blockIdx.x * 256 + threadIdx.x;
    if (i < nn) row_start[i] += bsum[blockIdx.x];
    if (i == 0) row_start[nn] = ne;
}

// ---------- fused: fill (4-edge MLP) + layer-1 MFMA GEMM ----------
// fill blocks: col_idx[row_start[d]+rank[e]] = src[e], 4 edges/thread.
// gemm blocks: y-table (bf16 pairs, row stride 512B) = (A_fp32 @ W)*dis.
// Independent outputs (col_idx in d_out; y-table in X). Interleaved roles.
__global__ __launch_bounds__(256) void k_fill_mgemm(
    // gemm args
    const float* __restrict__ A, const float* __restrict__ W,
    uint32* __restrict__ yt, const float* __restrict__ rowscale, int M,
    // fill args
    const int* __restrict__ src, const int* __restrict__ dst,
    const int* __restrict__ rank, const int* __restrict__ row_start,
    int* __restrict__ col_idx, int ne, int nn,
    // role split
    int nfill, int ngemm) {
    __shared__ uint4 Bf[4][8][64];  // gemm role only (32KB)

    int bid = blockIdx.x;
    int both2 = 2 * (nfill < ngemm ? nfill : ngemm);
    bool isfill;
    int idx;
    if (bid < both2) { isfill = (bid & 1) == 0; idx = bid >> 1; }
    else { isfill = nfill > ngemm; idx = (both2 >> 1) + (bid - both2); }

    int t = threadIdx.x;

    if (isfill) {
        long long base = ((long long)idx * 256 + t) * 4;
        if (base + 4 <= (long long)ne) {
            int4 d4 = *(const int4*)(dst + base);
            int4 s4 = *(const int4*)(src + base);
            int4 r4 = *(const int4*)(rank + base);
            int dd[4] = {d4.x, d4.y, d4.z, d4.w};
            int ss[4] = {s4.x, s4.y, s4.z, s4.w};
            int rr[4] = {r4.x, r4.y, r4.z, r4.w};
            int pp[4];
#pragma unroll
            for (int r = 0; r < 4; r++) {
                bool ok = (unsigned)dd[r] < (unsigned)nn;
                int dv = ok ? dd[r] : 0;
                int p = row_start[dv] + rr[r];  // 4 independent random loads
                pp[r] = ok ? p : -1;
            }
#pragma unroll
            for (int r = 0; r < 4; r++)
                if ((unsigned)pp[r] < (unsigned)ne) col_idx[pp[r]] = ss[r];
        } else {
            for (long long e = base; e < (long long)ne; e++) {
                int d = dst[e];
                if ((unsigned)d >= (unsigned)nn) continue;
                int p = row_start[d] + rank[e];
                if ((unsigned)p < (unsigned)ne) col_idx[p] = src[e];
            }
        }
        return;
    }

    // ---- gemm role: NOUT=128, INBF=false, OUTBF=true ----
    for (int e = t; e < 4 * 8 * 64; e += 256) {
        int kc = e / (8 * 64);
        int rem = e - kc * (8 * 64);
        int ct = rem >> 6;
        int l  = rem & 63;
        int k0 = kc * 32 + (l >> 4) * 8;
        int c  = ct * 16 + (l & 15);
        u16 us[8];
#pragma unroll
        for (int i = 0; i < 8; i++) us[i] = f2bf(W[(size_t)(k0 + i) * 128 + c]);
        uint4 u;
        u.x = (uint32)us[0] | ((uint32)us[1] << 16);
        u.y = (uint32)us[2] | ((uint32)us[3] << 16);
        u.z = (uint32)us[4] | ((uint32)us[5] << 16);
        u.w = (uint32)us[6] | ((uint32)us[7] << 16);
        Bf[kc][ct][l] = u;
    }
    __syncthreads();

    int lane = t & 63, wv = t >> 6;
    int r0 = idx * 64 + wv * 16;
    if (r0 >= M) return;

    int arow = r0 + (lane & 15);
    if (arow >= M) arow = M - 1;
    U4S8 af[4];
#pragma unroll
    for (int kc = 0; kc < 4; kc++) {
        const float4* s = (const float4*)(A + (size_t)arow * FD + kc * 32 + (lane >> 4) * 8);
        float4 v0 = s[0], v1 = s[1];
        uint4 u;
        u.x = (uint32)f2bf(v0.x) | ((uint32)f2bf(v0.y) << 16);
        u.y = (uint32)f2bf(v0.z) | ((uint32)f2bf(v0.w) << 16);
        u.z = (uint32)f2bf(v1.x) | ((uint32)f2bf(v1.y) << 16);
        u.w = (uint32)f2bf(v1.z) | ((uint32)f2bf(v1.w) << 16);
        af[kc].u = u;
    }

    f32x4 acc[8];
#pragma unroll
    for (int ct = 0; ct < 8; ct++) acc[ct] = f32x4{0.f, 0.f, 0.f, 0.f};
#pragma unroll
    for (int kc = 0; kc < 4; kc++) {
#pragma unroll
        for (int ct = 0; ct < 8; ct++) {
            U4S8 b;
            b.u = Bf[kc][ct][lane];
            acc[ct] = __builtin_amdgcn_mfma_f32_16x16x32_bf16(af[kc].s, b.s, acc[ct], 0, 0, 0);
        }
    }

    int rb = r0 + (lane >> 4) * 4;
#pragma unroll
    for (int r = 0; r < 4; r++) {
        int row = rb + r;
        int rc = row < M ? row : M - 1;
        float rs = rowscale[rc];
#pragma unroll
        for (int ct = 0; ct < 8; ct++) {
            float v = acc[ct][r] * rs;
            float vn = __shfl_xor(v, 1);
            if (!(lane & 1) && row < M) {
                uint32 word = (uint32)f2bf(v) | ((uint32)f2bf(vn) << 16);
                yt[(size_t)row * 128 + (ct * 16 + (lane & 15)) / 2] = word;
            }
        }
    }
}

// ---------- MFMA GEMM (standalone, layers 2 + head) ----------
template <int NOUT, bool INBF, bool OUTBF>
__global__ __launch_bounds__(256) void k_mgemm(const void* __restrict__ Ap,
                                               const float* __restrict__ W,
                                               void* __restrict__ out,
                                               const float* __restrict__ bias,
                                               const float* __restrict__ rowscale,
                                               int M) {
    constexpr int NT = (NOUT + 15) / 16;  // col tiles
    __shared__ uint4 Bf[4][NT][64];       // [kc][ct][lane] fragment-order W

    int t = threadIdx.x;
    for (int e = t; e < 4 * NT * 64; e += 256) {
        int kc = e / (NT * 64);
        int rem = e - kc * (NT * 64);
        int ct = rem >> 6;
        int l  = rem & 63;
        int k0 = kc * 32 + (l >> 4) * 8;
        int c  = ct * 16 + (l & 15);
        u16 us[8];
#pragma unroll
        for (int i = 0; i < 8; i++)
            us[i] = (c < NOUT) ? f2bf(W[(size_t)(k0 + i) * NOUT + c]) : (u16)0;
        uint4 u;
        u.x = (uint32)us[0] | ((uint32)us[1] << 16);
        u.y = (uint32)us[2] | ((uint32)us[3] << 16);
        u.z = (uint32)us[4] | ((uint32)us[5] << 16);
        u.w = (uint32)us[6] | ((uint32)us[7] << 16);
        Bf[kc][ct][l] = u;
    }
    __syncthreads();

    int lane = t & 63, wv = t >> 6;
    int r0 = blockIdx.x * 64 + wv * 16;
    if (r0 >= M) return;

    int arow = r0 + (lane & 15);
    if (arow >= M) arow = M - 1;
    U4S8 af[4];
    if (INBF) {
        const u16* A = (const u16*)Ap;
#pragma unroll
        for (int kc = 0; kc < 4; kc++)
            af[kc].u = *(const uint4*)(A + (size_t)arow * FD + kc * 32 + (lane >> 4) * 8);
    } else {
        const float* A = (const float*)Ap;
#pragma unroll
        for (int kc = 0; kc < 4; kc++) {
            const float4* s = (const float4*)(A + (size_t)arow * FD + kc * 32 + (lane >> 4) * 8);
            float4 v0 = s[0], v1 = s[1];
            uint4 u;
            u.x = (uint32)f2bf(v0.x) | ((uint32)f2bf(v0.y) << 16);
            u.y = (uint32)f2bf(v0.z) | ((uint32)f2bf(v0.w) << 16);
            u.z = (uint32)f2bf(v1.x) | ((uint32)f2bf(v1.y) << 16);
            u.w = (uint32)f2bf(v1.z) | ((uint32)f2bf(v1.w) << 16);
            af[kc].u = u;
        }
    }

    f32x4 acc[NT];
#pragma unroll
    for (int ct = 0; ct < NT; ct++) acc[ct] = f32x4{0.f, 0.f, 0.f, 0.f};
#pragma unroll
    for (int kc = 0; kc < 4; kc++) {
#pragma unroll
        for (int ct = 0; ct < NT; ct++) {
            U4S8 b;
            b.u = Bf[kc][ct][lane];
            acc[ct] = __builtin_amdgcn_mfma_f32_16x16x32_bf16(af[kc].s, b.s, acc[ct], 0, 0, 0);
        }
    }

    int rb = r0 + (lane >> 4) * 4;
    if (OUTBF) {
        uint32* yt = (uint32*)out;
#pragma unroll
        for (int r = 0; r < 4; r++) {
            int row = rb + r;
            int rc = row < M ? row : M - 1;
            float rs = rowscale ? rowscale[rc] : 1.f;
#pragma unroll
            for (int ct = 0; ct < NT; ct++) {
                float v = acc[ct][r] * rs;
                float vn = __shfl_xor(v, 1);
                if (!(lane & 1) && row < M) {
                    uint32 word = (uint32)f2bf(v) | ((uint32)f2bf(vn) << 16);
                    yt[(size_t)row * 128 + (ct * 16 + (lane & 15)) / 2] = word;
                }
            }
        }
    } else {
        float* fo = (float*)out;
#pragma unroll
        for (int r = 0; r < 4; r++) {
            int row = rb + r;
            if (row >= M) continue;
#pragma unroll
            for (int ct = 0; ct < NT; ct++) {
                int c = ct * 16 + (lane & 15);
                if (c < NOUT) {
                    float v = acc[ct][r];
                    if (bias) v += bias[c];
                    fo[(size_t)row * NOUT + c] = v;
                }
            }
        }
    }
}

// ---------- Aggregation: out[d] = relu(dis[d]*(y[d] + sum_{e:dst=d} y[src]) + b) ----------
// 4 nodes/wave, 16 lanes x dwordx4 gathers (1KB/instr), depth-8 rounds,
// idx broadcast via __shfl, persistent grid-stride. (R14, unchanged.)
__global__ __launch_bounds__(256) void k_agg(const uint32* __restrict__ yt,
                                             const float* __restrict__ dis,
                                             const int* __restrict__ row_start,
                                             const int* __restrict__ col_idx,
                                             const float* __restrict__ bias,
                                             uint32* __restrict__ outp,
                                             int nn, int ne) {
    int lane = threadIdx.x & 63;
    int wid  = threadIdx.x >> 6;   // wave in block (0..3)
    int g    = lane >> 4;          // node group (0..3)
    int sub  = lane & 15;          // word-slice owner

    float2 bq[4];
#pragma unroll
    for (int k = 0; k < 4; k++) bq[k] = *(const float2*)(bias + (sub * 4 + k) * 2);

    const int stride = gridDim.x * 16;
    for (int n0 = blockIdx.x * 16 + wid * 4; n0 < nn; n0 += stride) {
        int n = n0 + g;
        bool act = n < nn;
        int nl = act ? n : 0;

        float di = dis[nl];
        int jb = row_start[nl];
        int je = row_start[nl + 1];
        if (!act) { jb = 0; je = 0; }
        if (jb < 0) jb = 0;
        if (je > ne) je = ne;
        int deg = je - jb; if (deg < 0) deg = 0;
        int je1 = je - 1;

        uint4 sv = *(const uint4*)(yt + (size_t)nl * 128 + sub * 4);
        float a0 = bfLo(sv.x), a1 = bfHi(sv.x);
        float a2 = bfLo(sv.y), a3 = bfHi(sv.y);
        float a4 = bfLo(sv.z), a5 = bfHi(sv.z);
        float a6 = bfLo(sv.w), a7 = bfHi(sv.w);

        int m = deg;
        m = max(m, __shfl_xor(m, 16));
        m = max(m, __shfl_xor(m, 32));

        for (int base = 0; base < m; base += 8) {
            int jj = jb + base + (sub & 7);
            int jc = jj < je ? jj : je1;
            if (jc < 0) jc = 0;
            int sl = col_idx[jc];
            if ((unsigned)sl >= (unsigned)nn) sl = -1;  // poison

            int ss[8];
            float ww[8];
#pragma unroll
            for (int r = 0; r < 8; r++) {
                int s = __shfl(sl, (lane & 48) + r);
                ww[r] = (base + r < deg && s >= 0) ? 1.f : 0.f;
                ss[r] = s >= 0 ? s : 0;
            }
            uint4 uu[8];
#pragma unroll
            for (int r = 0; r < 8; r++)
                uu[r] = *(const uint4*)(yt + (size_t)ss[r] * 128 + sub * 4);
#pragma unroll
            for (int r = 0; r < 8; r++) {
                float wg = ww[r];
                a0 = fmaf(bfLo(uu[r].x), wg, a0); a1 = fmaf(bfHi(uu[r].x), wg, a1);
                a2 = fmaf(bfLo(uu[r].y), wg, a2); a3 = fmaf(bfHi(uu[r].y), wg, a3);
                a4 = fmaf(bfLo(uu[r].z), wg, a4); a5 = fmaf(bfHi(uu[r].z), wg, a5);
                a6 = fmaf(bfLo(uu[r].w), wg, a6); a7 = fmaf(bfHi(uu[r].w), wg, a7);
            }
        }

        if (act) {
            float r0 = fmaxf(fmaf(a0, di, bq[0].x), 0.f);
            float r1 = fmaxf(fmaf(a1, di, bq[0].y), 0.f);
            float r2 = fmaxf(fmaf(a2, di, bq[1].x), 0.f);
            float r3 = fmaxf(fmaf(a3, di, bq[1].y), 0.f);
            float r4 = fmaxf(fmaf(a4, di, bq[2].x), 0.f);
            float r5 = fmaxf(fmaf(a5, di, bq[2].y), 0.f);
            float r6 = fmaxf(fmaf(a6, di, bq[3].x), 0.f);
            float r7 = fmaxf(fmaf(a7, di, bq[3].y), 0.f);
            uint4 o;
            o.x = (uint32)f2bf(r0) | ((uint32)f2bf(r1) << 16);
            o.y = (uint32)f2bf(r2) | ((uint32)f2bf(r3) << 16);
            o.z = (uint32)f2bf(r4) | ((uint32)f2bf(r5) << 16);
            o.w = (uint32)f2bf(r6) | ((uint32)f2bf(r7) << 16);
            *(uint4*)(outp + (size_t)n * 64 + sub * 4) = o;
        }
    }
}

// ---------- launch ----------
static inline char* carve(char*& p, size_t bytes) {
    char* r = p;
    p += (bytes + 255) & ~(size_t)255;
    return r;
}

extern "C" void kernel_launch(void* const* d_in, const int* in_sizes, int n_in,
                              void* d_out, int out_size, void* d_ws, size_t ws_size,
                              hipStream_t stream) {
    const long long outn = out_size;
    float* dout = (float*)d_out;
    if (n_in < 8) {
        k_beacon<<<(int)((outn + 255) / 256), 256, 0, stream>>>(dout, outn, 888.f);
        return;
    }
    float* X        = (float*)d_in[0];  // fp32; reused as y-table scratch (harness restores)
    const int* ei   = (const int*)d_in[1];
    const float* W1 = (const float*)d_in[2];
    const float* b1 = (const float*)d_in[3];
    const float* W2 = (const float*)d_in[4];
    const float* b2 = (const float*)d_in[5];
    const float* Wl = (const float*)d_in[6];
    const float* bl = (const float*)d_in[7];

    const int H1 = in_sizes[3];                      // 128
    const int F  = in_sizes[2] / (H1 > 0 ? H1 : 1);  // 128
    const int NC = in_sizes[7];                      // 40
    const int NN = in_sizes[0] / (F > 0 ? F : 1);
    const int NE = in_sizes[1] / 2;
    if (NN <= 0 || NE <= 0 || F != FD || H1 != FD || NC != 40 ||
        (long long)NN * FD != in_sizes[0] || outn != (long long)NN * NC) {
        k_beacon<<<(int)((outn + 255) / 256), 256, 0, stream>>>(dout, outn, 888.f);
        return;
    }

    // Reference-literal edge convention: msg flows src=ei[0] -> dst=ei[1].
    const int* src = ei;
    const int* dst = ei + NE;
    const int nb = (NN + 255) / 256;

    // ---- workspace carve ----
    char* p = (char*)d_ws;
    int*   cnt       = (int*)  carve(p, ((size_t)NN + 1) * 4);  // +1 junk slot
    float* dis       = (float*)carve(p, (size_t)NN * 4);
    int*   bsum      = (int*)  carve(p, (size_t)nb * 4);
    int*   row_start = (int*)  carve(p, ((size_t)NN + 1) * 4);
    u16*   bufA      = (u16*)  carve(p, (size_t)NN * FD * 2);  // bf16 inter-stage
    size_t needed = (size_t)(p - (char*)d_ws);
    // col_idx (NE*4) + rank (NE*4) in the dead output buffer when they fit.
    bool in_out = (size_t)NE * 8 <= (size_t)outn * 4;
    int* col_idx;
    int* rank;
    if (in_out) {
        col_idx = (int*)d_out;
        rank = (int*)((char*)d_out + (size_t)NE * 4);
    } else {
        col_idx = (int*)carve(p, (size_t)NE * 4);
        rank = (int*)carve(p, (size_t)NE * 4);
        needed = (size_t)(p - (char*)d_ws);
    }
    if (needed > ws_size) {
        k_beacon<<<(int)((outn + 255) / 256), 256, 0, stream>>>(dout, outn, 999.f);
        return;
    }

    const int ecb = (int)(((long long)NE + 1023) / 1024);  // 4 edges/thread
    const int gemm_blocks = (NN + 63) / 64;
    int agg_blocks = (NN + 15) / 16;
    if (agg_blocks > 2048) agg_blocks = 2048;

    // ---- CSR build (by dst) ----
    hipMemsetAsync(cnt, 0, ((size_t)NN + 1) * 4, stream);
    hipMemsetAsync(col_idx, 0xFF, (size_t)NE * 4, stream);
    k_count<<<ecb, 256, 0, stream>>>(dst, cnt, rank, NE, NN);
    k_scan_a<<<nb, 256, 0, stream>>>(cnt, row_start, bsum, dis, NN);
    k_scan_b<<<1, 512, 0, stream>>>(bsum, nb);
    k_scan_c<<<nb, 256, 0, stream>>>(row_start, bsum, NN, NE);

    // ---- fused: fill (4-edge MLP) + layer-1 GEMM (X -> y-table, in-place) ----
    k_fill_mgemm<<<ecb + gemm_blocks, 256, 0, stream>>>(
        X, W1, (uint32*)X, dis, NN,
        src, dst, rank, row_start, col_idx, NE, NN,
        ecb, gemm_blocks);

    // ---- layer 1 agg: bufA = relu(dis*agg + b1) bf16 ----
    k_agg<<<agg_blocks, 256, 0, stream>>>((const uint32*)X, dis, row_start, col_idx,
                                          b1, (uint32*)bufA, NN, NE);
    // ---- layer 2: X <- bf16 y-table of (bufA @ W2)*dis (MFMA); bufA = relu(...) ----
    k_mgemm<128, true, true><<<gemm_blocks, 256, 0, stream>>>(bufA, W2, X, nullptr, dis, NN);
    k_agg<<<agg_blocks, 256, 0, stream>>>((const uint32*)X, dis, row_start, col_idx,
                                          b2, (uint32*)bufA, NN, NE);
    // ---- head: d_out = bufA @ Wl + bl (MFMA, fp32 out; col_idx/rank dead) ----
    k_mgemm<40, true, false><<<gemm_blocks, 256, 0, stream>>>(bufA, Wl, dout, bl, nullptr, NN);
}

// Round 8
// 362.642 us; speedup vs baseline: 1.0554x; 1.0554x over previous
//
#include <hip/hip_runtime.h>

// GCN: 2x GCNConv(128->128, relu) + linear(128->40).
// R17: k_count is at the device-atomic THROUGHPUT ceiling (68us at 1 or 4
// atomics/lane in flight, 46% or 68% occ -> 23.5G atomics/s pipe limit).
// Can't shrink it; hide it instead:
//   - count || layer-1 GEMM fused (4:1 block-role interleave). gemm1 can't
//     use dis (not computed yet) -> y-table is UNSCALED; agg now applies
//     dis[s] as the gather weight (idx lane loads dis[sl], broadcasts via
//     shfl) and dis[d] on self + post-scale. Same math, reassociated.
//   - fill back to standalone (R16 fusion made it inherit gemm's VGPR/LDS
//     footprint and regressed); 4-edge MLP batching kept.
//   - col_idx 0xFF memset dropped: scan_c now sets row_start[nn] to the
//     VALID-edge total (from cnt), so agg never reads unwritten slots.
// gemm2/head/agg structure otherwise unchanged from R15/R16 (absmax 1.95e-3).

typedef unsigned int uint32;
typedef unsigned short u16;

#define FD 128  // F_IN = H1 = H2 = 128 (structural)

using short8 = __attribute__((ext_vector_type(8))) short;
using f32x4  = __attribute__((ext_vector_type(4))) float;

union U4S8 { uint4 u; short8 s; };

__device__ __forceinline__ u16 f2bf(float f) {  // fp32 -> bf16 bits, RNE
    uint32 u = __float_as_uint(f);
    uint32 r = ((u >> 16) & 1u) + 0x7FFFu;
    return (u16)((u + r) >> 16);
}
__device__ __forceinline__ float bf2f(u16 s) { return __uint_as_float((uint32)s << 16); }
__device__ __forceinline__ float bfLo(uint32 w) { return __uint_as_float(w << 16); }
__device__ __forceinline__ float bfHi(uint32 w) { return __uint_as_float(w & 0xFFFF0000u); }

__global__ void k_beacon(float* __restrict__ out, long long n, float val) {
    long long i = (long long)blockIdx.x * 256 + threadIdx.x;
    if (i < n) out[i] = val;
}

// ---------- fused: count (atomic-ceiling-bound) + layer-1 MFMA GEMM ----------
// count role: rank[e] = atomicAdd(&cnt[dst[e]],1); junk slot nn for poison.
// gemm role: UNSCALED bf16 y-table (row stride 512B) = A_fp32 @ W, in-place
// in A (block reads its 64 rows fully before writing the same byte range).
__global__ __launch_bounds__(256) void k_cnt_mgemm(
    // count args
    const int* __restrict__ dst, int* __restrict__ cnt, int* __restrict__ rank,
    int ne, int nn,
    // gemm args
    const float* __restrict__ A, const float* __restrict__ W,
    uint32* __restrict__ yt, int M,
    int ngemm) {
    __shared__ uint4 Bf[4][8][64];  // gemm role only (32KB)

    int bid = blockIdx.x;
    int g5 = bid / 5;
    bool isg = ((bid % 5) == 0) && (g5 < ngemm);
    int t = threadIdx.x;

    if (!isg) {
        int idx = bid - (g5 + 1 < ngemm ? g5 + 1 : ngemm);
        int e = idx * 256 + t;
        if (e < ne) {
            int d = dst[e];
            int a = ((unsigned)d < (unsigned)nn) ? d : nn;
            rank[e] = atomicAdd(&cnt[a], 1);
        }
        return;
    }

    // ---- gemm role (idx = g5): NOUT=128, fp32 in, unscaled bf16 y-table out ----
    int idx = g5;
    for (int e = t; e < 4 * 8 * 64; e += 256) {
        int kc = e / (8 * 64);
        int rem = e - kc * (8 * 64);
        int ct = rem >> 6;
        int l  = rem & 63;
        int k0 = kc * 32 + (l >> 4) * 8;
        int c  = ct * 16 + (l & 15);
        u16 us[8];
#pragma unroll
        for (int i = 0; i < 8; i++) us[i] = f2bf(W[(size_t)(k0 + i) * 128 + c]);
        uint4 u;
        u.x = (uint32)us[0] | ((uint32)us[1] << 16);
        u.y = (uint32)us[2] | ((uint32)us[3] << 16);
        u.z = (uint32)us[4] | ((uint32)us[5] << 16);
        u.w = (uint32)us[6] | ((uint32)us[7] << 16);
        Bf[kc][ct][l] = u;
    }
    __syncthreads();

    int lane = t & 63, wv = t >> 6;
    int r0 = idx * 64 + wv * 16;
    if (r0 >= M) return;

    int arow = r0 + (lane & 15);
    if (arow >= M) arow = M - 1;
    U4S8 af[4];
#pragma unroll
    for (int kc = 0; kc < 4; kc++) {
        const float4* s = (const float4*)(A + (size_t)arow * FD + kc * 32 + (lane >> 4) * 8);
        float4 v0 = s[0], v1 = s[1];
        uint4 u;
        u.x = (uint32)f2bf(v0.x) | ((uint32)f2bf(v0.y) << 16);
        u.y = (uint32)f2bf(v0.z) | ((uint32)f2bf(v0.w) << 16);
        u.z = (uint32)f2bf(v1.x) | ((uint32)f2bf(v1.y) << 16);
        u.w = (uint32)f2bf(v1.z) | ((uint32)f2bf(v1.w) << 16);
        af[kc].u = u;
    }

    f32x4 acc[8];
#pragma unroll
    for (int ct = 0; ct < 8; ct++) acc[ct] = f32x4{0.f, 0.f, 0.f, 0.f};
#pragma unroll
    for (int kc = 0; kc < 4; kc++) {
#pragma unroll
        for (int ct = 0; ct < 8; ct++) {
            U4S8 b;
            b.u = Bf[kc][ct][lane];
            acc[ct] = __builtin_amdgcn_mfma_f32_16x16x32_bf16(af[kc].s, b.s, acc[ct], 0, 0, 0);
        }
    }

    int rb = r0 + (lane >> 4) * 4;
#pragma unroll
    for (int r = 0; r < 4; r++) {
        int row = rb + r;
#pragma unroll
        for (int ct = 0; ct < 8; ct++) {
            float v = acc[ct][r];
            float vn = __shfl_xor(v, 1);
            if (!(lane & 1) && row < M) {
                uint32 word = (uint32)f2bf(v) | ((uint32)f2bf(vn) << 16);
                yt[(size_t)row * 128 + (ct * 16 + (lane & 15)) / 2] = word;
            }
        }
    }
}

// scan_a + dis fused: block-local exclusive scan of cnt, plus dis=rsqrt(cnt+1).
__global__ void k_scan_a(const int* __restrict__ cnt, int* __restrict__ row_start,
                         int* __restrict__ bsum, float* __restrict__ dis, int nn) {
    __shared__ int tmp[256];
    int t = threadIdx.x;
    int i = blockIdx.x * 256 + t;
    int v = (i < nn) ? cnt[i] : 0;
    if (i < nn) dis[i] = rsqrtf((float)(v + 1));  // +1 self-loop
    tmp[t] = v;
    __syncthreads();
    for (int off = 1; off < 256; off <<= 1) {
        int x = (t >= off) ? tmp[t - off] : 0;
        __syncthreads();
        tmp[t] += x;
        __syncthreads();
    }
    if (i < nn) row_start[i] = tmp[t] - v;
    if (t == 255) bsum[blockIdx.x] = tmp[255];
}

__global__ void k_scan_b(int* bsum, int nb) {  // chunked exclusive scan, any nb
    __shared__ int tmp[512];
    __shared__ int carry;
    int t = threadIdx.x;
    if (t == 0) carry = 0;
    __syncthreads();
    for (int base = 0; base < nb; base += 512) {
        int i = base + t;
        int v = (i < nb) ? bsum[i] : 0;
        tmp[t] = v;
        __syncthreads();
        for (int off = 1; off < 512; off <<= 1) {
            int x = (t >= off) ? tmp[t - off] : 0;
            __syncthreads();
            tmp[t] += x;
            __syncthreads();
        }
        if (i < nb) bsum[i] = tmp[t] - v + carry;
        __syncthreads();
        if (t == 0) carry += tmp[511];
        __syncthreads();
    }
}

// R17: row_start[nn] = total VALID edges (so dropped col_idx memset is safe).
__global__ void k_scan_c(int* __restrict__ row_start, const int* __restrict__ bsum,
                         const int* __restrict__ cnt, int nn) {
    int i = blockIdx.x * 256 + threadIdx.x;
    if (i < nn) {
        int r = row_start[i] + bsum[blockIdx.x];
        row_start[i] = r;
        if (i == nn - 1) row_start[nn] = r + cnt[i];
    }
}

// Atomic-free fill, 4-edge MLP: col_idx[row_start[d]+rank[e]] = src[e].
__global__ __launch_bounds__(256) void k_fill(const int* __restrict__ src,
                                              const int* __restrict__ dst,
                                              const int* __restrict__ rank,
                                              const int* __restrict__ row_start,
                                              int* __restrict__ col_idx,
                                              int ne, int nn) {
    long long base = ((long long)blockIdx.x * 256 + threadIdx.x) * 4;
    if (base + 4 <= (long long)ne) {
        int4 d4 = *(const int4*)(dst + base);
        int4 s4 = *(const int4*)(src + base);
        int4 r4 = *(const int4*)(rank + base);
        int dd[4] = {d4.x, d4.y, d4.z, d4.w};
        int ss[4] = {s4.x, s4.y, s4.z, s4.w};
        int rr[4] = {r4.x, r4.y, r4.z, r4.w};
        int pp[4];
#pragma unroll
        for (int r = 0; r < 4; r++) {
            bool ok = (unsigned)dd[r] < (unsigned)nn;
            int dv = ok ? dd[r] : 0;
            int p = row_start[dv] + rr[r];  // 4 independent random loads
            pp[r] = ok ? p : -1;
        }
#pragma unroll
        for (int r = 0; r < 4; r++)
            if ((unsigned)pp[r] < (unsigned)ne) col_idx[pp[r]] = ss[r];
    } else {
        for (long long e = base; e < (long long)ne; e++) {
            int d = dst[e];
            if ((unsigned)d >= (unsigned)nn) continue;
            int p = row_start[d] + rank[e];
            if ((unsigned)p < (unsigned)ne) col_idx[p] = src[e];
        }
    }
}

// ---------- MFMA GEMM (standalone, layer 2 + head) ----------
template <int NOUT, bool INBF, bool OUTBF>
__global__ __launch_bounds__(256) void k_mgemm(const void* __restrict__ Ap,
                                               const float* __restrict__ W,
                                               void* __restrict__ out,
                                               const float* __restrict__ bias,
                                               int M) {
    constexpr int NT = (NOUT + 15) / 16;  // col tiles
    __shared__ uint4 Bf[4][NT][64];       // [kc][ct][lane] fragment-order W

    int t = threadIdx.x;
    for (int e = t; e < 4 * NT * 64; e += 256) {
        int kc = e / (NT * 64);
        int rem = e - kc * (NT * 64);
        int ct = rem >> 6;
        int l  = rem & 63;
        int k0 = kc * 32 + (l >> 4) * 8;
        int c  = ct * 16 + (l & 15);
        u16 us[8];
#pragma unroll
        for (int i = 0; i < 8; i++)
            us[i] = (c < NOUT) ? f2bf(W[(size_t)(k0 + i) * NOUT + c]) : (u16)0;
        uint4 u;
        u.x = (uint32)us[0] | ((uint32)us[1] << 16);
        u.y = (uint32)us[2] | ((uint32)us[3] << 16);
        u.z = (uint32)us[4] | ((uint32)us[5] << 16);
        u.w = (uint32)us[6] | ((uint32)us[7] << 16);
        Bf[kc][ct][l] = u;
    }
    __syncthreads();

    int lane = t & 63, wv = t >> 6;
    int r0 = blockIdx.x * 64 + wv * 16;
    if (r0 >= M) return;

    int arow = r0 + (lane & 15);
    if (arow >= M) arow = M - 1;
    U4S8 af[4];
    if (INBF) {
        const u16* A = (const u16*)Ap;
#pragma unroll
        for (int kc = 0; kc < 4; kc++)
            af[kc].u = *(const uint4*)(A + (size_t)arow * FD + kc * 32 + (lane >> 4) * 8);
    } else {
        const float* A = (const float*)Ap;
#pragma unroll
        for (int kc = 0; kc < 4; kc++) {
            const float4* s = (const float4*)(A + (size_t)arow * FD + kc * 32 + (lane >> 4) * 8);
            float4 v0 = s[0], v1 = s[1];
            uint4 u;
            u.x = (uint32)f2bf(v0.x) | ((uint32)f2bf(v0.y) << 16);
            u.y = (uint32)f2bf(v0.z) | ((uint32)f2bf(v0.w) << 16);
            u.z = (uint32)f2bf(v1.x) | ((uint32)f2bf(v1.y) << 16);
            u.w = (uint32)f2bf(v1.z) | ((uint32)f2bf(v1.w) << 16);
            af[kc].u = u;
        }
    }

    f32x4 acc[NT];
#pragma unroll
    for (int ct = 0; ct < NT; ct++) acc[ct] = f32x4{0.f, 0.f, 0.f, 0.f};
#pragma unroll
    for (int kc = 0; kc < 4; kc++) {
#pragma unroll
        for (int ct = 0; ct < NT; ct++) {
            U4S8 b;
            b.u = Bf[kc][ct][lane];
            acc[ct] = __builtin_amdgcn_mfma_f32_16x16x32_bf16(af[kc].s, b.s, acc[ct], 0, 0, 0);
        }
    }

    int rb = r0 + (lane >> 4) * 4;
    if (OUTBF) {
        uint32* yt = (uint32*)out;
#pragma unroll
        for (int r = 0; r < 4; r++) {
            int row = rb + r;
#pragma unroll
            for (int ct = 0; ct < NT; ct++) {
                float v = acc[ct][r];
                float vn = __shfl_xor(v, 1);
                if (!(lane & 1) && row < M) {
                    uint32 word = (uint32)f2bf(v) | ((uint32)f2bf(vn) << 16);
                    yt[(size_t)row * 128 + (ct * 16 + (lane & 15)) / 2] = word;
                }
            }
        }
    } else {
        float* fo = (float*)out;
#pragma unroll
        for (int r = 0; r < 4; r++) {
            int row = rb + r;
            if (row >= M) continue;
#pragma unroll
            for (int ct = 0; ct < NT; ct++) {
                int c = ct * 16 + (lane & 15);
                if (c < NOUT) {
                    float v = acc[ct][r];
                    if (bias) v += bias[c];
                    fo[(size_t)row * NOUT + c] = v;
                }
            }
        }
    }
}

// ---------- Aggregation (dis-weighted gathers; y-table UNSCALED) ----------
// out[d] = relu( dis[d] * ( dis[d]*y[d] + sum_{e:dst=d} dis[src]*y[src] ) + b )
// 4 nodes/wave, 16 lanes x dwordx4 gathers, depth-8, idx+weight broadcast
// via shfl, persistent grid-stride.
__global__ __launch_bounds__(256) void k_agg(const uint32* __restrict__ yt,
                                             const float* __restrict__ dis,
                                             const int* __restrict__ row_start,
                                             const int* __restrict__ col_idx,
                                             const float* __restrict__ bias,
                                             uint32* __restrict__ outp,
                                             int nn, int ne) {
    int lane = threadIdx.x & 63;
    int wid  = threadIdx.x >> 6;   // wave in block (0..3)
    int g    = lane >> 4;          // node group (0..3)
    int sub  = lane & 15;          // word-slice owner

    float2 bq[4];
#pragma unroll
    for (int k = 0; k < 4; k++) bq[k] = *(const float2*)(bias + (sub * 4 + k) * 2);

    const int stride = gridDim.x * 16;
    for (int n0 = blockIdx.x * 16 + wid * 4; n0 < nn; n0 += stride) {
        int n = n0 + g;
        bool act = n < nn;
        int nl = act ? n : 0;

        float di = dis[nl];
        int jb = row_start[nl];
        int je = row_start[nl + 1];
        if (!act) { jb = 0; je = 0; }
        if (jb < 0) jb = 0;
        if (je > ne) je = ne;
        int deg = je - jb; if (deg < 0) deg = 0;
        int je1 = je - 1;

        // self term: dis[n] * y[n]
        uint4 sv = *(const uint4*)(yt + (size_t)nl * 128 + sub * 4);
        float a0 = bfLo(sv.x) * di, a1 = bfHi(sv.x) * di;
        float a2 = bfLo(sv.y) * di, a3 = bfHi(sv.y) * di;
        float a4 = bfLo(sv.z) * di, a5 = bfHi(sv.z) * di;
        float a6 = bfLo(sv.w) * di, a7 = bfHi(sv.w) * di;

        int m = deg;
        m = max(m, __shfl_xor(m, 16));
        m = max(m, __shfl_xor(m, 32));

        for (int base = 0; base < m; base += 8) {
            int jj = jb + base + (sub & 7);
            int jc = jj < je ? jj : je1;
            if (jc < 0) jc = 0;
            int sl = col_idx[jc];
            float ds = 0.f;
            if ((unsigned)sl < (unsigned)nn) ds = dis[sl];  // poison -> 0
            else sl = 0;

            int ss[8];
            float ww[8];
#pragma unroll
            for (int r = 0; r < 8; r++) {
                int srcLane = (lane & 48) + r;
                int s = __shfl(sl, srcLane);
                float w = __shfl(ds, srcLane);
                ww[r] = (base + r < deg) ? w : 0.f;
                ss[r] = s;
            }
            uint4 uu[8];
#pragma unroll
            for (int r = 0; r < 8; r++)
                uu[r] = *(const uint4*)(yt + (size_t)ss[r] * 128 + sub * 4);
#pragma unroll
            for (int r = 0; r < 8; r++) {
                float wg = ww[r];
                a0 = fmaf(bfLo(uu[r].x), wg, a0); a1 = fmaf(bfHi(uu[r].x), wg, a1);
                a2 = fmaf(bfLo(uu[r].y), wg, a2); a3 = fmaf(bfHi(uu[r].y), wg, a3);
                a4 = fmaf(bfLo(uu[r].z), wg, a4); a5 = fmaf(bfHi(uu[r].z), wg, a5);
                a6 = fmaf(bfLo(uu[r].w), wg, a6); a7 = fmaf(bfHi(uu[r].w), wg, a7);
            }
        }

        if (act) {
            float r0 = fmaxf(fmaf(a0, di, bq[0].x), 0.f);
            float r1 = fmaxf(fmaf(a1, di, bq[0].y), 0.f);
            float r2 = fmaxf(fmaf(a2, di, bq[1].x), 0.f);
            float r3 = fmaxf(fmaf(a3, di, bq[1].y), 0.f);
            float r4 = fmaxf(fmaf(a4, di, bq[2].x), 0.f);
            float r5 = fmaxf(fmaf(a5, di, bq[2].y), 0.f);
            float r6 = fmaxf(fmaf(a6, di, bq[3].x), 0.f);
            float r7 = fmaxf(fmaf(a7, di, bq[3].y), 0.f);
            uint4 o;
            o.x = (uint32)f2bf(r0) | ((uint32)f2bf(r1) << 16);
            o.y = (uint32)f2bf(r2) | ((uint32)f2bf(r3) << 16);
            o.z = (uint32)f2bf(r4) | ((uint32)f2bf(r5) << 16);
            o.w = (uint32)f2bf(r6) | ((uint32)f2bf(r7) << 16);
            *(uint4*)(outp + (size_t)n * 64 + sub * 4) = o;
        }
    }
}

// ---------- launch ----------
static inline char* carve(char*& p, size_t bytes) {
    char* r = p;
    p += (bytes + 255) & ~(size_t)255;
    return r;
}

extern "C" void kernel_launch(void* const* d_in, const int* in_sizes, int n_in,
                              void* d_out, int out_size, void* d_ws, size_t ws_size,
                              hipStream_t stream) {
    const long long outn = out_size;
    float* dout = (float*)d_out;
    if (n_in < 8) {
        k_beacon<<<(int)((outn + 255) / 256), 256, 0, stream>>>(dout, outn, 888.f);
        return;
    }
    float* X        = (float*)d_in[0];  // fp32; reused as y-table scratch (harness restores)
    const int* ei   = (const int*)d_in[1];
    const float* W1 = (const float*)d_in[2];
    const float* b1 = (const float*)d_in[3];
    const float* W2 = (const float*)d_in[4];
    const float* b2 = (const float*)d_in[5];
    const float* Wl = (const float*)d_in[6];
    const float* bl = (const float*)d_in[7];

    const int H1 = in_sizes[3];                      // 128
    const int F  = in_sizes[2] / (H1 > 0 ? H1 : 1);  // 128
    const int NC = in_sizes[7];                      // 40
    const int NN = in_sizes[0] / (F > 0 ? F : 1);
    const int NE = in_sizes[1] / 2;
    if (NN <= 0 || NE <= 0 || F != FD || H1 != FD || NC != 40 ||
        (long long)NN * FD != in_sizes[0] || outn != (long long)NN * NC) {
        k_beacon<<<(int)((outn + 255) / 256), 256, 0, stream>>>(dout, outn, 888.f);
        return;
    }

    // Reference-literal edge convention: msg flows src=ei[0] -> dst=ei[1].
    const int* src = ei;
    const int* dst = ei + NE;
    const int nb = (NN + 255) / 256;

    // ---- workspace carve ----
    char* p = (char*)d_ws;
    int*   cnt       = (int*)  carve(p, ((size_t)NN + 1) * 4);  // +1 junk slot
    float* dis       = (float*)carve(p, (size_t)NN * 4);
    int*   bsum      = (int*)  carve(p, (size_t)nb * 4);
    int*   row_start = (int*)  carve(p, ((size_t)NN + 1) * 4);
    u16*   bufA      = (u16*)  carve(p, (size_t)NN * FD * 2);  // bf16 inter-stage
    size_t needed = (size_t)(p - (char*)d_ws);
    // col_idx (NE*4) + rank (NE*4) in the dead output buffer when they fit.
    bool in_out = (size_t)NE * 8 <= (size_t)outn * 4;
    int* col_idx;
    int* rank;
    if (in_out) {
        col_idx = (int*)d_out;
        rank = (int*)((char*)d_out + (size_t)NE * 4);
    } else {
        col_idx = (int*)carve(p, (size_t)NE * 4);
        rank = (int*)carve(p, (size_t)NE * 4);
        needed = (size_t)(p - (char*)d_ws);
    }
    if (needed > ws_size) {
        k_beacon<<<(int)((outn + 255) / 256), 256, 0, stream>>>(dout, outn, 999.f);
        return;
    }

    const int ecb1 = (NE + 255) / 256;                     // count: 1 edge/thread
    const int ecb4 = (int)(((long long)NE + 1023) / 1024); // fill: 4 edges/thread
    const int gemm_blocks = (NN + 63) / 64;
    int agg_blocks = (NN + 15) / 16;
    if (agg_blocks > 2048) agg_blocks = 2048;

    // ---- CSR build + layer-1 GEMM overlapped ----
    hipMemsetAsync(cnt, 0, ((size_t)NN + 1) * 4, stream);
    k_cnt_mgemm<<<ecb1 + gemm_blocks, 256, 0, stream>>>(
        dst, cnt, rank, NE, NN,
        X, W1, (uint32*)X, NN, gemm_blocks);
    k_scan_a<<<nb, 256, 0, stream>>>(cnt, row_start, bsum, dis, NN);
    k_scan_b<<<1, 512, 0, stream>>>(bsum, nb);
    k_scan_c<<<nb, 256, 0, stream>>>(row_start, bsum, cnt, NN);
    k_fill<<<ecb4, 256, 0, stream>>>(src, dst, rank, row_start, col_idx, NE, NN);

    // ---- layer 1 agg: bufA = relu(dis*(dis*y_self + sum dis_s*y_s) + b1) ----
    k_agg<<<agg_blocks, 256, 0, stream>>>((const uint32*)X, dis, row_start, col_idx,
                                          b1, (uint32*)bufA, NN, NE);
    // ---- layer 2: X <- unscaled bf16 y-table of bufA @ W2 (MFMA) ----
    k_mgemm<128, true, true><<<gemm_blocks, 256, 0, stream>>>(bufA, W2, X, nullptr, NN);
    k_agg<<<agg_blocks, 256, 0, stream>>>((const uint32*)X, dis, row_start, col_idx,
                                          b2, (uint32*)bufA, NN, NE);
    // ---- head: d_out = bufA @ Wl + bl (MFMA, fp32 out; col_idx/rank dead) ----
    k_mgemm<40, true, false><<<gemm_blocks, 256, 0, stream>>>(bufA, Wl, dout, bl, NN);
}